// Round 6
// baseline (108.964 us; speedup 1.0000x reference)
//
#include <hip/hip_runtime.h>
#include <hip/hip_bf16.h>

#define NUM_AGES 100
#define FEAT 512
#define BATCH 4096
#define EPSF 1e-6f
#define INV_T 10.0f
#define INV_NORM (1.0f / ((float)BATCH * (float)(BATCH - 1)))

#define BM 128
#define BN 128
#define BK 64
// kept tiles: by <= bx, bx in [0,32) -> 32*33/2 = 528; 528 = 8*66 -> bijective XCD chunking
#define NTILES 528

typedef __bf16 bf16_t;
typedef __bf16 v8bf __attribute__((ext_vector_type(8)));
typedef float v4f __attribute__((ext_vector_type(4)));

// async global->LDS, 16B per lane; LDS dest is wave-uniform base + lane*16
__device__ __forceinline__ void async16(const void* g, void* l) {
  __builtin_amdgcn_global_load_lds(
      (const __attribute__((address_space(1))) void*)g,
      (__attribute__((address_space(3))) void*)l, 16, 0, 0);
}

// ---------------- kernel 1: per-sample prep (inline rank + pre-swizzle) ---
// Block j computes rank(j) = #{k: a_k < a_j or (a_k==a_j and k<j)} (stable,
// bijective) and writes to sorted position `rank`. zb/wb are stored
// XOR-swizzled: within each 128B (64-elem) K-slab, logical 16B granule g of
// row r sits at physical position g ^ (r&7). pair_kernel's contiguous
// global_load_lds staging then lands a bank-balanced LDS layout (2 lanes per
// bank-quad = free) with zero change to its global access pattern.
__global__ __launch_bounds__(256) void prep_kernel(
    const float* __restrict__ z, const int* __restrict__ ages,
    const float* __restrict__ proxies,
    bf16_t* __restrict__ zb, bf16_t* __restrict__ wb,
    float* __restrict__ sq, float* __restrict__ hd,
    int* __restrict__ ages_s, float* __restrict__ out)
{
  int j = blockIdx.x;          // original sample index
  int t = threadIdx.x;
  if (j == 0 && t == 0) out[0] = 0.0f;   // pair_kernel accumulates into out

  int araw = ages[j];
  int a = araw < 0 ? 0 : (araw > NUM_AGES - 1 ? NUM_AGES - 1 : araw);
  const float* cc = proxies + (size_t)a * FEAT;
  const float* cn = proxies + (size_t)(a + 1 > NUM_AGES - 1 ? NUM_AGES - 1 : a + 1) * FEAT;
  const float* cp = proxies + (size_t)(a - 1 < 0 ? 0 : a - 1) * FEAT;
  const float* zr = z + (size_t)j * FEAT;

  // ---- rank of sample j in stable age order ----
  int cnt = 0;
#pragma unroll
  for (int e = 0; e < BATCH / 256; ++e) {
    int k = t + e * 256;
    int ak = ages[k];
    cnt += (ak < araw || (ak == araw && k < j)) ? 1 : 0;
  }

  // ---- vectorized per-sample math: thread t owns cols 2t, 2t+1 ----
  int c0 = 2 * t;
  float2 cc2 = *(const float2*)(cc + c0);
  float2 cn2 = *(const float2*)(cn + c0);
  float2 cp2 = *(const float2*)(cp + c0);
  float2 z2  = *(const float2*)(zr + c0);
  float df0 = cn2.x - cc2.x, df1 = cn2.y - cc2.y;
  float db0 = cp2.x - cc2.x, db1 = cp2.y - cc2.y;
  float s_ff = df0 * df0 + df1 * df1;
  float s_bb = db0 * db0 + db1 * db1;
  float s_zz = z2.x * z2.x + z2.y * z2.y;
  float s_zf = z2.x * df0 + z2.y * df1;
  float s_zb = z2.x * db0 + z2.y * db1;

  float fcnt = (float)cnt;
#pragma unroll
  for (int off = 32; off > 0; off >>= 1) {
    s_ff += __shfl_down(s_ff, off, 64);
    s_bb += __shfl_down(s_bb, off, 64);
    s_zz += __shfl_down(s_zz, off, 64);
    s_zf += __shfl_down(s_zf, off, 64);
    s_zb += __shfl_down(s_zb, off, 64);
    fcnt += __shfl_down(fcnt, off, 64);
  }
  __shared__ float red[4][6];
  int wv = t >> 6, lane = t & 63;
  if (lane == 0) {
    red[wv][0] = s_ff; red[wv][1] = s_bb; red[wv][2] = s_zz;
    red[wv][3] = s_zf; red[wv][4] = s_zb; red[wv][5] = fcnt;
  }
  __syncthreads();
  float ff = red[0][0] + red[1][0] + red[2][0] + red[3][0];
  float bb = red[0][1] + red[1][1] + red[2][1] + red[3][1];
  float zz = red[0][2] + red[1][2] + red[2][2] + red[3][2];
  float zdf = red[0][3] + red[1][3] + red[2][3] + red[3][3];
  float zdb = red[0][4] + red[1][4] + red[2][4] + red[3][4];
  int rank = (int)(red[0][5] + red[1][5] + red[2][5] + red[3][5]);

  float rf = 1.0f / (sqrtf(ff) + EPSF);
  float rb = 1.0f / (sqrtf(bb) + EPSF);
  int key = rank & 7;
  // swizzled column for the granule holding cols {2t, 2t+1}
  int c2s = (c0 & ~63) | (((((c0 >> 3) & 7) ^ key) << 3)) | (c0 & 7);
  float w0 = db0 * rb - df0 * rf;
  float w1 = db1 * rb - df1 * rf;
  union { bf16_t h[2]; unsigned u; } uz, uw;
  uz.h[0] = (bf16_t)z2.x; uz.h[1] = (bf16_t)z2.y;
  uw.h[0] = (bf16_t)w0;   uw.h[1] = (bf16_t)w1;
  *(unsigned*)((char*)zb + ((size_t)rank * FEAT + c2s) * 2) = uz.u;
  *(unsigned*)((char*)wb + ((size_t)rank * FEAT + c2s) * 2) = uw.u;
  if (t == 0) {
    sq[rank] = zz;
    hd[rank] = rb * zdb - rf * zdf;
    ages_s[rank] = araw;
  }
}

// ---------------- kernel 2: fused pairwise tile (upper-tri band only) ----
// v6 = v5 tile + v2's PROVEN plain double-buffer schedule (no inline-asm:
// v3b showed fences/setprio break compiler pipelining and regress).
// Each K-iter: issue stage(t+1) into the other buffer, compute buf[cur],
// ONE __syncthreads. The barrier's implicit vmcnt(0) now waits on loads
// that had a full compute phase (~1300cy) in flight -> L2 latency hidden
// (v5's single-buffer drained loads issued the SAME iter = hard stall,
// the m233 "2-phase stall" pattern).
// Cost: dbuf 2x48KB + aux ~= 101KB -> 1 block/CU, 8 waves (2/SIMD).
// launch_bounds(512,2) -> 256-reg cap >= ~124 needed: no spill possible
// (v4's (512,6) demanded 85 regs and spilled accumulators to scratch).
// Per-CU/K-iter bound: max(MFMA 1241cy, LDS-read ~1500cy, stage 830cy).
// XCD-chunked column order kept (proven: FETCH 24.5->14.5MB).
__global__ __launch_bounds__(512, 2) void pair_kernel(
    const bf16_t* __restrict__ zb, const bf16_t* __restrict__ wb,
    const float* __restrict__ sq, const float* __restrict__ hd,
    const int* __restrict__ ages, float* __restrict__ out)
{
  // per buffer: A 128x64 bf16 = 16K | Z 128x64 = 16K | W 128x64 = 16K
  __shared__ __attribute__((aligned(16))) char lds[2][49152];
  __shared__ float s_sqi[BM];
  __shared__ int   s_agei[BM];
  __shared__ float s_sqj[BN];
  __shared__ float s_hdj[BN];
  __shared__ int   s_agej[BN];
  __shared__ float wsum[8];

  int t = threadIdx.x;
  int wv = t >> 6, lane = t & 63;

  // ---- tile decode: XCD chunk + column-major triangle (by <= bx) ----
  // column bx holds bx+1 tiles (by = 0..bx); XCD x gets ids [66x, 66x+66)
  int id = (blockIdx.x & 7) * (NTILES / 8) + (blockIdx.x >> 3);
  int bx = 0, rem = id;
  while (rem >= bx + 1) { rem -= bx + 1; ++bx; }
  int by = rem;
  int i0 = by * BM, j0 = bx * BN;

  int wm = wv >> 2, wn = wv & 3;        // wave grid 2x4: 64 rows x 32 cols each
  int lm = lane & 15, q = lane >> 4;
  // swizzled granule byte offsets for the two 32-elem slabs (key = lm&7)
  int psw0 = ((q     ) ^ (lm & 7)) * 16;
  int psw1 = ((q + 4 ) ^ (lm & 7)) * 16;

  // staging: per async16, lane l covers row (l>>3), physical granule (l&7)
  // of an 8-row x 128B chunk (contiguous copy preserves prep's swizzle).
  int loff = (lane >> 3) * FEAT + (lane & 7) * 8;   // bf16 elements
  const bf16_t* baseA = zb + (size_t)i0 * FEAT + loff;
  const bf16_t* baseZ = zb + (size_t)j0 * FEAT + loff;
  const bf16_t* baseW = wb + (size_t)j0 * FEAT + loff;

  // stage one K-tile (6 loads/wave: 2 A + 2 Z + 2 W chunks of 8 rows)
  auto STAGE = [&](int k0, char* nb) {
#pragma unroll
    for (int c = 0; c < 2; ++c) {
      int chunk = wv * 2 + c;
      async16(baseA + (size_t)chunk * 8 * FEAT + k0, nb + chunk * 1024);
      async16(baseZ + (size_t)chunk * 8 * FEAT + k0, nb + 16384 + chunk * 1024);
      async16(baseW + (size_t)chunk * 8 * FEAT + k0, nb + 32768 + chunk * 1024);
    }
  };

  // ---- prologue: stage tile 0; aux loads overlap the drain ----
  STAGE(0, lds[0]);

  if (t < BM) {
    s_sqi[t] = sq[i0 + t];
    s_agei[t] = ages[i0 + t];
  } else if (t < BM + BN) {
    int u = t - BM;
    s_sqj[u] = sq[j0 + u];
    s_hdj[u] = hd[j0 + u];
    s_agej[u] = ages[j0 + u];
  }

  v4f accG[4][2], accH[4][2];
#pragma unroll
  for (int a = 0; a < 4; ++a)
#pragma unroll
    for (int b = 0; b < 2; ++b) {
      accG[a][b] = (v4f){0.f, 0.f, 0.f, 0.f};
      accH[a][b] = (v4f){0.f, 0.f, 0.f, 0.f};
    }

  __syncthreads();   // implicit vmcnt(0): tile 0 staged (one-time cost)

  int cur = 0;
  for (int it = 0; it < FEAT / BK; ++it) {
    // issue next tile's loads FIRST: they fly during this iter's compute,
    // so the end-of-iter barrier's vmcnt(0) finds them already landed
    if (it + 1 < FEAT / BK) STAGE((it + 1) * BK, lds[cur ^ 1]);

    const char* cb = lds[cur];
#pragma unroll
    for (int s = 0; s < 2; ++s) {
      int psw = s ? psw1 : psw0;
      v8bf afr[4], bz[2], bw[2];
#pragma unroll
      for (int mi = 0; mi < 4; ++mi) {
        int r = wm * 64 + mi * 16 + lm;
        afr[mi] = *(const v8bf*)(cb + r * 128 + psw);
      }
#pragma unroll
      for (int ni = 0; ni < 2; ++ni) {
        int r = wn * 32 + ni * 16 + lm;
        bz[ni] = *(const v8bf*)(cb + 16384 + r * 128 + psw);
        bw[ni] = *(const v8bf*)(cb + 32768 + r * 128 + psw);
      }
#pragma unroll
      for (int mi = 0; mi < 4; ++mi)
#pragma unroll
        for (int ni = 0; ni < 2; ++ni) {
          accG[mi][ni] = __builtin_amdgcn_mfma_f32_16x16x32_bf16(afr[mi], bz[ni], accG[mi][ni], 0, 0, 0);
          accH[mi][ni] = __builtin_amdgcn_mfma_f32_16x16x32_bf16(afr[mi], bw[ni], accH[mi][ni], 0, 0, 0);
        }
    }

    // one barrier per iter: RAW (next tile staged) + WAR (this buffer free)
    __syncthreads();
    cur ^= 1;
  }

  // epilogue: C/D layout col = lane&15 (-> j), row = q*4 + reg (-> i)
  float tsum = 0.f;
#pragma unroll
  for (int ni = 0; ni < 2; ++ni) {
    int jl = wn * 32 + ni * 16 + lm;
    float sqj = s_sqj[jl];
    float hdj = s_hdj[jl];
    int aj = s_agej[jl];
#pragma unroll
    for (int mi = 0; mi < 4; ++mi) {
#pragma unroll
      for (int r = 0; r < 4; ++r) {
        int il = wm * 64 + mi * 16 + q * 4 + r;
        float g = accG[mi][ni][r];
        float h = accH[mi][ni][r];
        float d2 = fmaxf(s_sqi[il] + sqj - 2.0f * g, 1e-12f);
        float rs = __builtin_amdgcn_rsqf(d2);
        float arg = (h - hdj) * INV_T * rs;
        float sp = fmaxf(arg, 0.0f) + __logf(1.0f + __expf(-fabsf(arg)));
        tsum += (s_agei[il] < aj) ? sp : 0.0f;
      }
    }
  }

#pragma unroll
  for (int off = 32; off > 0; off >>= 1) tsum += __shfl_down(tsum, off, 64);
  if (lane == 0) wsum[wv] = tsum;
  __syncthreads();
  if (t == 0) {
    float bs = 0.f;
#pragma unroll
    for (int w = 0; w < 8; ++w) bs += wsum[w];
    atomicAdd(out, bs * INV_NORM);
  }
}

extern "C" void kernel_launch(void* const* d_in, const int* in_sizes, int n_in,
                              void* d_out, int out_size, void* d_ws, size_t ws_size,
                              hipStream_t stream) {
  const float* z = (const float*)d_in[0];
  const int* ages = (const int*)d_in[1];
  const float* proxies = (const float*)d_in[2];
  float* out = (float*)d_out;

  char* ws = (char*)d_ws;
  bf16_t* zb = (bf16_t*)ws;                                   // 4 MB
  bf16_t* wb = (bf16_t*)(ws + (size_t)4 * 1024 * 1024);       // 4 MB
  size_t o = (size_t)8 * 1024 * 1024;
  float* sq      = (float*)(ws + o);            // 16 KB
  float* hd      = (float*)(ws + o + 16384);    // 16 KB
  int*   ages_s  = (int*)  (ws + o + 32768);    // 16 KB

  prep_kernel<<<BATCH, 256, 0, stream>>>(z, ages, proxies, zb, wb, sq, hd, ages_s, out);
  pair_kernel<<<NTILES, 512, 0, stream>>>(zb, wb, sq, hd, ages_s, out);
}

// Round 8
// 99.226 us; speedup vs baseline: 1.0981x; 1.0981x over previous
//
#include <hip/hip_runtime.h>
#include <hip/hip_bf16.h>

#define NUM_AGES 100
#define FEAT 512
#define BATCH 4096
#define EPSF 1e-6f
#define INV_T 10.0f
#define INV_NORM (1.0f / ((float)BATCH * (float)(BATCH - 1)))

#define BM 128
#define BN 128
#define BK 64
// kept tiles: by <= bx, bx in [0,32) -> 32*33/2 = 528 = 8*66 (bijective XCD chunking)
#define NTILES 528

typedef __bf16 bf16_t;
typedef __bf16 v8bf __attribute__((ext_vector_type(8)));
typedef float v4f __attribute__((ext_vector_type(4)));

// async global->LDS, 16B per lane; LDS dest is wave-uniform base + lane*16
__device__ __forceinline__ void async16(const void* g, void* l) {
  __builtin_amdgcn_global_load_lds(
      (const __attribute__((address_space(1))) void*)g,
      (__attribute__((address_space(3))) void*)l, 16, 0, 0);
}

// ---------------- kernel 1: prep, wave-per-sample (v8 rewrite) -----------
// v7's fusion of prep+pair into one cooperative kernel FAILED (absmax 0.35):
// __threadfence + grid.sync is not a proven substitute for the kernel-
// boundary cross-XCD L2 flush on this part -> stay two-kernel (boundary =
// guaranteed release/acquire), but keep the faster prep:
//   * 512 blocks x 8 waves, one WAVE per sample (vs 4096 tiny blocks)
//   * ages[4096] staged once per block into LDS: ages traffic 67MB -> 8MB
//   * rank scan via LDS int4; all reductions are 64-lane butterflies
//     (no cross-wave LDS reduction, single barrier)
//   * lane owns 8 cols: float4 math, one 16B store each to zb/wb
// Same rank predicate (stable, bijective), same pre-swizzle: granule
// g=(c0>>3)&7 of row `rank` goes to physical g ^ (rank&7) in its 64-col
// K-slab -> pair_kernel's contiguous global_load_lds staging lands the
// bank-balanced LDS layout unchanged.
__global__ __launch_bounds__(512) void prep_kernel(
    const float* __restrict__ z, const int* __restrict__ ages,
    const float* __restrict__ proxies,
    bf16_t* __restrict__ zb, bf16_t* __restrict__ wb,
    float* __restrict__ sq, float* __restrict__ hd,
    int* __restrict__ ages_s, float* __restrict__ out)
{
  __shared__ __attribute__((aligned(16))) int sa[BATCH];   // 16 KB
  int t = threadIdx.x;
  int wv = t >> 6, lane = t & 63;
  if (blockIdx.x == 0 && t == 0) out[0] = 0.0f;   // pair accumulates into out

  ((int4*)sa)[t]       = ((const int4*)ages)[t];
  ((int4*)sa)[t + 512] = ((const int4*)ages)[t + 512];
  __syncthreads();

  int j = blockIdx.x * 8 + wv;          // this wave's sample
  int araw = sa[j];

  // rank scan over LDS (each lane 16 int4s, wave covers all 4096)
  int cnt = 0;
  const int4* sa4 = (const int4*)sa;
#pragma unroll
  for (int e = 0; e < 16; ++e) {
    int idx = lane + 64 * e;
    int4 v = sa4[idx];
    int k = idx * 4;
    cnt += (v.x < araw || (v.x == araw && k     < j)) ? 1 : 0;
    cnt += (v.y < araw || (v.y == araw && k + 1 < j)) ? 1 : 0;
    cnt += (v.z < araw || (v.z == araw && k + 2 < j)) ? 1 : 0;
    cnt += (v.w < araw || (v.w == araw && k + 3 < j)) ? 1 : 0;
  }

  // per-lane 8 columns
  int a  = araw < 0 ? 0 : (araw > NUM_AGES - 1 ? NUM_AGES - 1 : araw);
  int an = a + 1 > NUM_AGES - 1 ? NUM_AGES - 1 : a + 1;
  int ap = a - 1 < 0 ? 0 : a - 1;
  int c0 = lane * 8;
  const float4* cc4 = (const float4*)(proxies + (size_t)a  * FEAT + c0);
  const float4* cn4 = (const float4*)(proxies + (size_t)an * FEAT + c0);
  const float4* cp4 = (const float4*)(proxies + (size_t)ap * FEAT + c0);
  const float4* zr4 = (const float4*)(z + (size_t)j * FEAT + c0);

  float zv[8], df[8], db[8];
  float ff = 0.f, bb = 0.f, zz = 0.f, zf = 0.f, zbs = 0.f;
#pragma unroll
  for (int h = 0; h < 2; ++h) {
    float4 c4 = cc4[h], n4 = cn4[h], p4 = cp4[h], z4 = zr4[h];
    float cA[4] = {c4.x, c4.y, c4.z, c4.w};
    float nA[4] = {n4.x, n4.y, n4.z, n4.w};
    float pA[4] = {p4.x, p4.y, p4.z, p4.w};
    float zA[4] = {z4.x, z4.y, z4.z, z4.w};
#pragma unroll
    for (int i2 = 0; i2 < 4; ++i2) {
      int i = h * 4 + i2;
      zv[i] = zA[i2];
      df[i] = nA[i2] - cA[i2];
      db[i] = pA[i2] - cA[i2];
      ff  += df[i] * df[i];
      bb  += db[i] * db[i];
      zz  += zv[i] * zv[i];
      zf  += zv[i] * df[i];
      zbs += zv[i] * db[i];
    }
  }

  // 64-lane butterfly: every lane ends with the full-row sums
#pragma unroll
  for (int off = 32; off > 0; off >>= 1) {
    ff  += __shfl_xor(ff,  off, 64);
    bb  += __shfl_xor(bb,  off, 64);
    zz  += __shfl_xor(zz,  off, 64);
    zf  += __shfl_xor(zf,  off, 64);
    zbs += __shfl_xor(zbs, off, 64);
    cnt += __shfl_xor(cnt, off, 64);
  }
  int rank = cnt;
  float rf = 1.0f / (sqrtf(ff) + EPSF);
  float rb = 1.0f / (sqrtf(bb) + EPSF);
  int key = rank & 7;
  int c2s = (c0 & ~63) | ((((c0 >> 3) & 7) ^ key) << 3);  // c0&7 == 0

  union { bf16_t h[8]; uint4 u; } uz, uw;
#pragma unroll
  for (int i = 0; i < 8; ++i) {
    uz.h[i] = (bf16_t)zv[i];
    uw.h[i] = (bf16_t)(db[i] * rb - df[i] * rf);
  }
  *(uint4*)((char*)zb + ((size_t)rank * FEAT + c2s) * 2) = uz.u;
  *(uint4*)((char*)wb + ((size_t)rank * FEAT + c2s) * 2) = uw.u;
  if (lane == 0) {
    sq[rank] = zz;
    hd[rank] = rb * zbs - rf * zf;
    ages_s[rank] = araw;
  }
}

// ---------------- kernel 2: fused pairwise tile (v5 verbatim, proven) ----
// 128x128 tile, 512 threads (2x4 wave grid, 64x32 per wave), single 48KB
// buffer, plain stage->sync->compute->sync (v3b proved asm fences regress),
// XCD-chunked column-major triangle order (proven: FETCH 24.5->14.5MB).
// launch_bounds(512,4): 128-reg cap, no spill (v4's (512,6) spilled).
__global__ __launch_bounds__(512, 4) void pair_kernel(
    const bf16_t* __restrict__ zb, const bf16_t* __restrict__ wb,
    const float* __restrict__ sq, const float* __restrict__ hd,
    const int* __restrict__ ages, float* __restrict__ out)
{
  // A: 128x64 bf16 = 16384 B | Z: 128x64 = 16384 B | W: 128x64 = 16384 B
  __shared__ __attribute__((aligned(16))) char lds[49152];
  __shared__ float s_sqi[BM];
  __shared__ int   s_agei[BM];
  __shared__ float s_sqj[BN];
  __shared__ float s_hdj[BN];
  __shared__ int   s_agej[BN];
  __shared__ float wsum[8];

  int t = threadIdx.x;
  int wv = t >> 6, lane = t & 63;

  // ---- tile decode: XCD chunk + column-major triangle (by <= bx) ----
  int id = (blockIdx.x & 7) * (NTILES / 8) + (blockIdx.x >> 3);
  int bx = 0, rem = id;
  while (rem >= bx + 1) { rem -= bx + 1; ++bx; }
  int by = rem;
  int i0 = by * BM, j0 = bx * BN;

  if (t < BM) {
    s_sqi[t] = sq[i0 + t];
    s_agei[t] = ages[i0 + t];
  } else if (t < BM + BN) {
    int u = t - BM;
    s_sqj[u] = sq[j0 + u];
    s_hdj[u] = hd[j0 + u];
    s_agej[u] = ages[j0 + u];
  }

  v4f accG[4][2], accH[4][2];
#pragma unroll
  for (int a = 0; a < 4; ++a)
#pragma unroll
    for (int b = 0; b < 2; ++b) {
      accG[a][b] = (v4f){0.f, 0.f, 0.f, 0.f};
      accH[a][b] = (v4f){0.f, 0.f, 0.f, 0.f};
    }

  int wm = wv >> 2, wn = wv & 3;        // wave grid 2x4: 64 rows x 32 cols each
  int lm = lane & 15, q = lane >> 4;
  int psw0 = ((q    ) ^ (lm & 7)) * 16;
  int psw1 = ((q + 4) ^ (lm & 7)) * 16;

  int loff = (lane >> 3) * FEAT + (lane & 7) * 8;   // bf16 elements
  const bf16_t* baseA = zb + (size_t)i0 * FEAT + loff;
  const bf16_t* baseZ = zb + (size_t)j0 * FEAT + loff;
  const bf16_t* baseW = wb + (size_t)j0 * FEAT + loff;

  for (int k0 = 0; k0 < FEAT; k0 += BK) {
    // A/Z/W: 16 chunks of 8 rows each; wave wv does chunks wv*2, wv*2+1
#pragma unroll
    for (int c = 0; c < 2; ++c) {
      int chunk = wv * 2 + c;
      async16(baseA + (size_t)chunk * 8 * FEAT + k0, lds + chunk * 1024);
      async16(baseZ + (size_t)chunk * 8 * FEAT + k0, lds + 16384 + chunk * 1024);
      async16(baseW + (size_t)chunk * 8 * FEAT + k0, lds + 32768 + chunk * 1024);
    }
    __syncthreads();   // implicit vmcnt(0): tile staged

#pragma unroll
    for (int s = 0; s < 2; ++s) {
      int psw = s ? psw1 : psw0;
      v8bf afr[4], bz[2], bw[2];
#pragma unroll
      for (int mi = 0; mi < 4; ++mi) {
        int r = wm * 64 + mi * 16 + lm;
        afr[mi] = *(const v8bf*)(lds + r * 128 + psw);
      }
#pragma unroll
      for (int ni = 0; ni < 2; ++ni) {
        int r = wn * 32 + ni * 16 + lm;
        bz[ni] = *(const v8bf*)(lds + 16384 + r * 128 + psw);
        bw[ni] = *(const v8bf*)(lds + 32768 + r * 128 + psw);
      }
#pragma unroll
      for (int mi = 0; mi < 4; ++mi)
#pragma unroll
        for (int ni = 0; ni < 2; ++ni) {
          accG[mi][ni] = __builtin_amdgcn_mfma_f32_16x16x32_bf16(afr[mi], bz[ni], accG[mi][ni], 0, 0, 0);
          accH[mi][ni] = __builtin_amdgcn_mfma_f32_16x16x32_bf16(afr[mi], bw[ni], accH[mi][ni], 0, 0, 0);
        }
    }
    __syncthreads();   // WAR: reads done before next iter's staging
  }

  // epilogue: C/D layout col = lane&15 (-> j), row = q*4 + reg (-> i)
  float tsum = 0.f;
#pragma unroll
  for (int ni = 0; ni < 2; ++ni) {
    int jl = wn * 32 + ni * 16 + lm;
    float sqj = s_sqj[jl];
    float hdj = s_hdj[jl];
    int aj = s_agej[jl];
#pragma unroll
    for (int mi = 0; mi < 4; ++mi) {
#pragma unroll
      for (int r = 0; r < 4; ++r) {
        int il = wm * 64 + mi * 16 + q * 4 + r;
        float g = accG[mi][ni][r];
        float h = accH[mi][ni][r];
        float d2 = fmaxf(s_sqi[il] + sqj - 2.0f * g, 1e-12f);
        float rs = __builtin_amdgcn_rsqf(d2);
        float arg = (h - hdj) * INV_T * rs;
        float sp = fmaxf(arg, 0.0f) + __logf(1.0f + __expf(-fabsf(arg)));
        tsum += (s_agei[il] < aj) ? sp : 0.0f;
      }
    }
  }

#pragma unroll
  for (int off = 32; off > 0; off >>= 1) tsum += __shfl_down(tsum, off, 64);
  if (lane == 0) wsum[wv] = tsum;
  __syncthreads();
  if (t == 0) {
    float bs = 0.f;
#pragma unroll
    for (int w = 0; w < 8; ++w) bs += wsum[w];
    atomicAdd(out, bs * INV_NORM);
  }
}

extern "C" void kernel_launch(void* const* d_in, const int* in_sizes, int n_in,
                              void* d_out, int out_size, void* d_ws, size_t ws_size,
                              hipStream_t stream) {
  const float* z = (const float*)d_in[0];
  const int* ages = (const int*)d_in[1];
  const float* proxies = (const float*)d_in[2];
  float* out = (float*)d_out;

  char* ws = (char*)d_ws;
  bf16_t* zb = (bf16_t*)ws;                                   // 4 MB
  bf16_t* wb = (bf16_t*)(ws + (size_t)4 * 1024 * 1024);       // 4 MB
  size_t o = (size_t)8 * 1024 * 1024;
  float* sq      = (float*)(ws + o);            // 16 KB
  float* hd      = (float*)(ws + o + 16384);    // 16 KB
  int*   ages_s  = (int*)  (ws + o + 32768);    // 16 KB

  prep_kernel<<<BATCH / 8, 512, 0, stream>>>(z, ages, proxies, zb, wb, sq, hd, ages_s, out);
  pair_kernel<<<NTILES, 512, 0, stream>>>(zb, wb, sq, hd, ages_s, out);
}